// Round 13
// baseline (85.776 us; speedup 1.0000x reference)
//
#include <hip/hip_runtime.h>

// RWKV-4 WKV forward. B=16, T=1024, C=2048, fp32.
// r11 structure (T-split chunked scan, 2-slot LDS ring via global_load_lds,
// one barrier/segment, counted vmcnt, nt y-stores) + VALU diet:
//  - exp2-space: w,u,k pre-scaled by log2(e); all exps are bare v_exp_f32
//  - z-phase computes the exclusive prefix accumulators ONCE (pP/pQ held in
//    unrolled registers); y-loop consumes them (no duplicate fma chains)
//  - v_max3 normalizer, strength-reduced y pointer
// vmcnt audit (per-wave FIFO; 4 w16 loads mid-seg + 8 nt stores end-seg):
//   newer-than-L_s at top-of-segment wait:
//     s==0: L_1(4) = 4
//     s==1: L_2(4) + st_0(8) = 12
//     2<=s<=14: st_{s-2} tail(8) + L_{s+1}(4) + st_{s-1}(8) = 20
//     s==15: st_13(8) + st_14(8) = 16
// Barrier audit: identical to r11 (T/S double-buffered by s&1, one barrier).

#define T_DIM 1024
#define CDIM  2048
#define CHUNK 8
#define WAVES 8
#define SEG   (WAVES * CHUNK)   // 64
#define NSEG  (T_DIM / SEG)     // 16
#define NEG_BIG -1e38f
#define LOG2E 1.4426950408889634f

typedef const __attribute__((address_space(1))) float* gp_t;
typedef __attribute__((address_space(3))) float* lp_t;

__global__ __launch_bounds__(WAVES * 64, 4) void wkv_fwd_kernel(
    const float* __restrict__ w, const float* __restrict__ u,
    const float* __restrict__ kk, const float* __restrict__ vv,
    float* __restrict__ y)
{
    __shared__ __align__(16) float lk[2][SEG][64];   // 32 KB
    __shared__ __align__(16) float lv[2][SEG][64];   // 32 KB
    __shared__ float Tp[2][WAVES][64], Tq[2][WAVES][64], To[2][WAVES][64]; // 12 KB
    __shared__ float Sp[2][64], Sq[2][64], So[2][64];                      // 1.5 KB

    const int lane = threadIdx.x & 63;
    const int wid  = threadIdx.x >> 6;
    const int b    = blockIdx.y;
    const int c0   = blockIdx.x * 64;

    // exp2-space: all log-domain quantities carry a log2(e) factor
    const float wc  = w[c0 + lane] * LOG2E;
    const float uc  = u[c0 + lane] * LOG2E;
    const float wCH = wc * (float)CHUNK;

    const size_t sbase = (size_t)b * T_DIM * CDIM + c0;  // slab base (t=0)
    const int rl = lane >> 4;           // row within 4-row group
    const int cl = (lane & 15) * 4;     // col dword
    const float* kgl = kk + sbase + (size_t)rl * CDIM + cl;
    const float* vgl = vv + sbase + (size_t)rl * CDIM + cl;
    float*       yp  = y  + sbase + lane;   // + t*CDIM

    if (wid == 0) { Sp[0][lane] = 0.f; Sq[0][lane] = 0.f; So[0][lane] = NEG_BIG; }

    // issue this wave's 8 rows of one segment: 2 k-loads + 2 v-loads (w16)
    auto issue_seg = [&](int s) {
        const int sl = s & 1;
#pragma unroll
        for (int g = 0; g < 2; ++g) {
            const size_t go = (size_t)(s * SEG + wid * CHUNK + 4 * g) * CDIM;
            __builtin_amdgcn_global_load_lds((gp_t)(kgl + go),
                (lp_t)&lk[sl][wid * CHUNK + 4 * g][0], 16, 0, 0);
            __builtin_amdgcn_global_load_lds((gp_t)(vgl + go),
                (lp_t)&lv[sl][wid * CHUNK + 4 * g][0], 16, 0, 0);
        }
    };

    issue_seg(0);
    issue_seg(1);

#pragma unroll 1
    for (int s = 0; s < NSEG; ++s) {
        const int sl = s & 1;

        // wait for MY segment-s loads (exact FIFO counts, audit above)
        if (s == 0)            asm volatile("s_waitcnt vmcnt(4)"  ::: "memory");
        else if (s == 1)       asm volatile("s_waitcnt vmcnt(12)" ::: "memory");
        else if (s == NSEG-1)  asm volatile("s_waitcnt vmcnt(16)" ::: "memory");
        else                   asm volatile("s_waitcnt vmcnt(20)" ::: "memory");
        __builtin_amdgcn_sched_barrier(0);

        // z-space precompute + SINGLE exclusive-prefix accumulator pass
        float uk[CHUNK], hh[CHUNK], vc[CHUNK], pP[CHUNK], pQ[CHUNK];
        float M = NEG_BIG, aP = 0.f, aQ = 0.f;
#pragma unroll
        for (int j = 0; j < CHUNK; ++j) {
            const float kt = lk[sl][wid * CHUNK + j][lane] * LOG2E;
            vc[j] = lv[sl][wid * CHUNK + j][lane];
            const float zj = fmaf((float)(-j), wc, kt);   // (k_j - j*w)*log2e
            uk[j] = uc + kt;
            const float dl = M - zj;
            const float cf = exp2f(fminf(dl, 0.f));       // carry factor
            const float df = exp2f(fminf(-dl, 0.f));      // new-term factor
            hh[j] = fmaf((float)(j - 1), wc, M);          // ((j-1)w + M_j)*l2e
            M = fmaxf(M, zj);
            pP[j] = aP; pQ[j] = aQ;                       // exclusive prefixes
            aP = fmaf(cf, aP, df * vc[j]);
            aQ = fmaf(cf, aQ, df);
        }
        const float Pt = aP, Qt = aQ;                     // inclusive totals

        // slot sl fully consumed into registers -> refill it for seg s+2
        asm volatile("s_waitcnt lgkmcnt(0)" ::: "memory");
        __builtin_amdgcn_sched_barrier(0);
        if (s + 2 < NSEG) issue_seg(s + 2);

        if (wid < WAVES - 1) {
            Tp[sl][wid][lane] = Pt; Tq[sl][wid][lane] = Qt;
            To[sl][wid][lane] = fmaf((float)(CHUNK - 1), wc, M);
        }

        // the one barrier: T(s) visible; vmem stays in flight
        asm volatile("s_waitcnt lgkmcnt(0)" ::: "memory");
        __builtin_amdgcn_s_barrier();

        // compose S_in = S_run ∘ T_0 ∘ ... ∘ T_{wid-1}
        float p = Sp[sl][lane], q = Sq[sl][lane], o = So[sl][lane];
        for (int j = 0; j < wid; ++j) {       // wave-uniform trip count
            const float Oj = To[sl][j][lane];
            const float a  = o + wCH;
            const float d  = a - Oj;
            const float e  = exp2f(-fabsf(d));
            const float sA = d >= 0.f ? 1.f : e;
            const float sB = d >= 0.f ? e : 1.f;
            p = fmaf(sA, p, sB * Tp[sl][j][lane]);
            q = fmaf(sA, q, sB * Tq[sl][j][lane]);
            o = fmaxf(a, Oj);
        }

        // new running state (compose result + own totals)
        if (wid == WAVES - 1) {
            const float Ot = fmaf((float)(CHUNK - 1), wc, M);
            const float a  = o + wCH;
            const float d  = a - Ot;
            const float e  = exp2f(-fabsf(d));
            const float sA = d >= 0.f ? 1.f : e;
            const float sB = d >= 0.f ? e : 1.f;
            Sp[1 - sl][lane] = fmaf(sA, p, sB * Pt);
            Sq[1 - sl][lane] = fmaf(sA, q, sB * Qt);
            So[1 - sl][lane] = fmaxf(a, Ot);
        }

        // y loop: exact per-step normalizer; prefixes pre-computed;
        // direct NON-TEMPORAL stores via strength-reduced row pointer
        float* yq = yp + (size_t)(s * SEG + wid * CHUNK) * CDIM;
#pragma unroll
        for (int j = 0; j < CHUNK; ++j) {
            const float g   = fmaf((float)j, wc, o);
            const float no  = fmaxf(fmaxf(g, hh[j]), uk[j]);   // v_max3
            const float ea  = exp2f(g - no);
            const float eb  = exp2f(hh[j] - no);
            const float ec  = exp2f(uk[j] - no);
            const float num = fmaf(ea, p, fmaf(eb, pP[j], ec * vc[j]));
            const float den = fmaf(ea, q, fmaf(eb, pQ[j], ec));
            __builtin_nontemporal_store(__fdividef(num, den), yq);
            yq += CDIM;
        }
    }
}

extern "C" void kernel_launch(void* const* d_in, const int* in_sizes, int n_in,
                              void* d_out, int out_size, void* d_ws, size_t ws_size,
                              hipStream_t stream) {
    // inputs: 0=B, 1=T, 2=C (scalars), 3=w[C], 4=u[C], 5=k[B*T*C], 6=v[B*T*C]
    const float* w = (const float*)d_in[3];
    const float* u = (const float*)d_in[4];
    const float* k = (const float*)d_in[5];
    const float* v = (const float*)d_in[6];
    float* y = (float*)d_out;

    const int B = in_sizes[5] / (T_DIM * CDIM);   // 16

    dim3 grid(CDIM / 64, B);
    dim3 block(WAVES * 64);
    wkv_fwd_kernel<<<grid, block, 0, stream>>>(w, u, k, v, y);
}

// Round 14
// 69.563 us; speedup vs baseline: 1.2331x; 1.2331x over previous
//
#include <hip/hip_runtime.h>

// RWKV-4 WKV forward. B=16, T=1024, C=2048, fp32.
// r11 structure (T-split chunked scan, 2-slot LDS ring via global_load_lds,
// one barrier/segment, counted vmcnt, nt y-stores) + corrected VALU diet:
//  - __builtin_amdgcn_exp2f: RAW v_exp_f32 (r13's exp2f hit the OCML precise
//    path with denormal fixup -> +30 VALU/t; this is the actual native op)
//  - log2-space: w,u,k pre-scaled by log2(e) once per channel
//  - z-phase single-exp trick: cf,df from one exp2(-|dl|) + 2 cndmasks
//  - prefix fusion: exclusive prefixes pP/pQ computed once in the z-phase,
//    y-loop consumes them (no duplicate fma chains)
// vmcnt audit (per-wave FIFO; 4 w16 loads mid-seg + 8 nt stores end-seg):
//   newer-than-L_s at top-of-segment wait:
//     s==0: L_1(4) = 4
//     s==1: L_2(4) + st_0(8) = 12
//     2<=s<=14: st_{s-2} tail(8) + L_{s+1}(4) + st_{s-1}(8) = 20
//     s==15: st_13(8) + st_14(8) = 16
// Barrier audit: identical to r11 (T/S double-buffered by s&1, one barrier).

#define T_DIM 1024
#define CDIM  2048
#define CHUNK 8
#define WAVES 8
#define SEG   (WAVES * CHUNK)   // 64
#define NSEG  (T_DIM / SEG)     // 16
#define NEG_BIG -1e38f
#define LOG2E 1.4426950408889634f

typedef const __attribute__((address_space(1))) float* gp_t;
typedef __attribute__((address_space(3))) float* lp_t;

__global__ __launch_bounds__(WAVES * 64, 4) void wkv_fwd_kernel(
    const float* __restrict__ w, const float* __restrict__ u,
    const float* __restrict__ kk, const float* __restrict__ vv,
    float* __restrict__ y)
{
    __shared__ __align__(16) float lk[2][SEG][64];   // 32 KB
    __shared__ __align__(16) float lv[2][SEG][64];   // 32 KB
    __shared__ float Tp[2][WAVES][64], Tq[2][WAVES][64], To[2][WAVES][64]; // 12 KB
    __shared__ float Sp[2][64], Sq[2][64], So[2][64];                      // 1.5 KB

    const int lane = threadIdx.x & 63;
    const int wid  = threadIdx.x >> 6;
    const int b    = blockIdx.y;
    const int c0   = blockIdx.x * 64;

    // log2-space: all log-domain quantities carry a log2(e) factor
    const float wc  = w[c0 + lane] * LOG2E;
    const float uc  = u[c0 + lane] * LOG2E;
    const float wCH = wc * (float)CHUNK;

    const size_t sbase = (size_t)b * T_DIM * CDIM + c0;  // slab base (t=0)
    const int rl = lane >> 4;           // row within 4-row group
    const int cl = (lane & 15) * 4;     // col dword
    const float* kgl = kk + sbase + (size_t)rl * CDIM + cl;
    const float* vgl = vv + sbase + (size_t)rl * CDIM + cl;
    float*       yp  = y  + sbase + lane;   // + t*CDIM

    if (wid == 0) { Sp[0][lane] = 0.f; Sq[0][lane] = 0.f; So[0][lane] = NEG_BIG; }

    // issue this wave's 8 rows of one segment: 2 k-loads + 2 v-loads (w16)
    auto issue_seg = [&](int s) {
        const int sl = s & 1;
#pragma unroll
        for (int g = 0; g < 2; ++g) {
            const size_t go = (size_t)(s * SEG + wid * CHUNK + 4 * g) * CDIM;
            __builtin_amdgcn_global_load_lds((gp_t)(kgl + go),
                (lp_t)&lk[sl][wid * CHUNK + 4 * g][0], 16, 0, 0);
            __builtin_amdgcn_global_load_lds((gp_t)(vgl + go),
                (lp_t)&lv[sl][wid * CHUNK + 4 * g][0], 16, 0, 0);
        }
    };

    issue_seg(0);
    issue_seg(1);

#pragma unroll 1
    for (int s = 0; s < NSEG; ++s) {
        const int sl = s & 1;

        // wait for MY segment-s loads (exact FIFO counts, audit above)
        if (s == 0)            asm volatile("s_waitcnt vmcnt(4)"  ::: "memory");
        else if (s == 1)       asm volatile("s_waitcnt vmcnt(12)" ::: "memory");
        else if (s == NSEG-1)  asm volatile("s_waitcnt vmcnt(16)" ::: "memory");
        else                   asm volatile("s_waitcnt vmcnt(20)" ::: "memory");
        __builtin_amdgcn_sched_barrier(0);

        // z-space precompute + SINGLE exclusive-prefix accumulator pass
        // (one exp2 per step: cf,df selected from exp2(-|dl|))
        float uk[CHUNK], hh[CHUNK], vc[CHUNK], pP[CHUNK], pQ[CHUNK];
        float M = NEG_BIG, aP = 0.f, aQ = 0.f;
#pragma unroll
        for (int j = 0; j < CHUNK; ++j) {
            const float kt = lk[sl][wid * CHUNK + j][lane] * LOG2E;
            vc[j] = lv[sl][wid * CHUNK + j][lane];
            const float zj = fmaf((float)(-j), wc, kt);   // (k_j - j*w)*log2e
            uk[j] = uc + kt;
            const float dl = M - zj;
            const float e  = __builtin_amdgcn_exp2f(-fabsf(dl));
            const float cf = dl >= 0.f ? 1.f : e;         // carry factor
            const float df = dl >= 0.f ? e : 1.f;         // new-term factor
            hh[j] = fmaf((float)(j - 1), wc, M);          // ((j-1)w + M_j)*l2e
            M = fmaxf(M, zj);
            pP[j] = aP; pQ[j] = aQ;                       // exclusive prefixes
            aP = fmaf(cf, aP, df * vc[j]);
            aQ = fmaf(cf, aQ, df);
        }
        const float Pt = aP, Qt = aQ;                     // inclusive totals

        // slot sl fully consumed into registers -> refill it for seg s+2
        asm volatile("s_waitcnt lgkmcnt(0)" ::: "memory");
        __builtin_amdgcn_sched_barrier(0);
        if (s + 2 < NSEG) issue_seg(s + 2);

        if (wid < WAVES - 1) {
            Tp[sl][wid][lane] = Pt; Tq[sl][wid][lane] = Qt;
            To[sl][wid][lane] = fmaf((float)(CHUNK - 1), wc, M);
        }

        // the one barrier: T(s) visible; vmem stays in flight
        asm volatile("s_waitcnt lgkmcnt(0)" ::: "memory");
        __builtin_amdgcn_s_barrier();

        // compose S_in = S_run ∘ T_0 ∘ ... ∘ T_{wid-1}
        float p = Sp[sl][lane], q = Sq[sl][lane], o = So[sl][lane];
        for (int j = 0; j < wid; ++j) {       // wave-uniform trip count
            const float Oj = To[sl][j][lane];
            const float a  = o + wCH;
            const float d  = a - Oj;
            const float e  = __builtin_amdgcn_exp2f(-fabsf(d));
            const float sA = d >= 0.f ? 1.f : e;
            const float sB = d >= 0.f ? e : 1.f;
            p = fmaf(sA, p, sB * Tp[sl][j][lane]);
            q = fmaf(sA, q, sB * Tq[sl][j][lane]);
            o = fmaxf(a, Oj);
        }

        // new running state (compose result + own totals)
        if (wid == WAVES - 1) {
            const float Ot = fmaf((float)(CHUNK - 1), wc, M);
            const float a  = o + wCH;
            const float d  = a - Ot;
            const float e  = __builtin_amdgcn_exp2f(-fabsf(d));
            const float sA = d >= 0.f ? 1.f : e;
            const float sB = d >= 0.f ? e : 1.f;
            Sp[1 - sl][lane] = fmaf(sA, p, sB * Pt);
            Sq[1 - sl][lane] = fmaf(sA, q, sB * Qt);
            So[1 - sl][lane] = fmaxf(a, Ot);
        }

        // y loop: exact per-step normalizer (max3); prefixes pre-computed;
        // direct NON-TEMPORAL stores via strength-reduced row pointer
        float* yq = yp + (size_t)(s * SEG + wid * CHUNK) * CDIM;
#pragma unroll
        for (int j = 0; j < CHUNK; ++j) {
            const float g   = fmaf((float)j, wc, o);
            const float no  = fmaxf(fmaxf(g, hh[j]), uk[j]);   // v_max3
            const float ea  = __builtin_amdgcn_exp2f(g - no);
            const float eb  = __builtin_amdgcn_exp2f(hh[j] - no);
            const float ec  = __builtin_amdgcn_exp2f(uk[j] - no);
            const float num = fmaf(ea, p, fmaf(eb, pP[j], ec * vc[j]));
            const float den = fmaf(ea, q, fmaf(eb, pQ[j], ec));
            __builtin_nontemporal_store(__fdividef(num, den), yq);
            yq += CDIM;
        }
    }
}

extern "C" void kernel_launch(void* const* d_in, const int* in_sizes, int n_in,
                              void* d_out, int out_size, void* d_ws, size_t ws_size,
                              hipStream_t stream) {
    // inputs: 0=B, 1=T, 2=C (scalars), 3=w[C], 4=u[C], 5=k[B*T*C], 6=v[B*T*C]
    const float* w = (const float*)d_in[3];
    const float* u = (const float*)d_in[4];
    const float* k = (const float*)d_in[5];
    const float* v = (const float*)d_in[6];
    float* y = (float*)d_out;

    const int B = in_sizes[5] / (T_DIM * CDIM);   // 16

    dim3 grid(CDIM / 64, B);
    dim3 block(WAVES * 64);
    wkv_fwd_kernel<<<grid, block, 0, stream>>>(w, u, k, v, y);
}